// Round 2
// baseline (163.363 us; speedup 1.0000x reference)
//
#include <hip/hip_runtime.h>
#include <hip/hip_bf16.h>

// Problem: WanChannelLinearAttention  B=2, C=512, T=2048, D=64
// Inputs/outputs are fp32 (reference dtypes). Round-1 NaN diagnosed as
// fp32-data-read-as-bf16; this version reads fp32.
// Stage 1: per-(b,t) linear attention over channels -> out_ws [B*T][C] (bf16)
//          + fused fp32->bf16 convert of w_proj (blocks 0..255)
// Stage 2: y = x + b_proj + W_proj @ out  via MFMA bf16 GEMM, fp32 epilogue

#define B_ 2
#define C_ 512
#define T_ 2048
#define D_ 64
#define BT_ (B_ * T_)

typedef __hip_bfloat16 bf16;
typedef __bf16 bf16x8v __attribute__((ext_vector_type(8)));
typedef float f32x4 __attribute__((ext_vector_type(4)));

__device__ __forceinline__ bf16 f2b(float v) { return __float2bfloat16(v); }

// elu(y)+1 == y>0 ? y+1 : exp(y)
__device__ __forceinline__ float phi(float y) {
    return y > 0.0f ? y + 1.0f : __expf(y);
}

__global__ __launch_bounds__(256) void attn_kernel(
    const float* __restrict__ x,
    const float* __restrict__ wq, const float* __restrict__ bq,
    const float* __restrict__ wk, const float* __restrict__ bk,
    const float* __restrict__ wv, const float* __restrict__ bv,
    const float* __restrict__ w_proj,
    bf16* __restrict__ out_ws, bf16* __restrict__ wbf)
{
    __shared__ float xs[C_];
    __shared__ float wqs[D_], bqs[D_];
    __shared__ float Sred[4][D_], Zred[4][D_];
    __shared__ float Sf[D_], Zf[D_];

    const int tid = threadIdx.x;
    const int bt = blockIdx.x;
    const int b = bt >> 11;          // T_ = 2048
    const int t = bt & (T_ - 1);

    // fused w_proj fp32->bf16 convert: 256 blocks x 256 threads x 1 float4
    if (bt < 256) {
        const float4 v = ((const float4*)w_proj)[bt * 256 + tid];
        bf16* dst = wbf + (size_t)(bt * 256 + tid) * 4;
        dst[0] = f2b(v.x); dst[1] = f2b(v.y); dst[2] = f2b(v.z); dst[3] = f2b(v.w);
    }

    // stage x[b, :, t] (strided gather) into LDS
    for (int c = tid; c < C_; c += 256)
        xs[c] = x[(size_t)b * C_ * T_ + (size_t)c * T_ + t];
    if (tid < D_) { wqs[tid] = wq[tid]; bqs[tid] = bq[tid]; }
    __syncthreads();

    // ---- phase 1: S[d], Z[d] ----
    const int d = tid & 63;
    const int g = tid >> 6;          // wave index = channel group
    const float wkd = wk[d], bkd = bk[d];
    const float wvs = wv[0], bvs = bv[0];
    float S = 0.0f, Z = 0.0f;
    const int c0 = g * 128;
    #pragma unroll 4
    for (int i = 0; i < 128; ++i) {
        const float xv = xs[c0 + i];          // wave-uniform -> LDS broadcast
        const float pk = phi(xv * wkd + bkd);
        const float vv = xv * wvs + bvs;
        S += pk * vv;
        Z += pk;
    }
    Sred[g][d] = S; Zred[g][d] = Z;
    __syncthreads();
    if (tid < D_) {
        const float s = Sred[0][tid] + Sred[1][tid] + Sred[2][tid] + Sred[3][tid];
        const float z = Zred[0][tid] + Zred[1][tid] + Zred[2][tid] + Zred[3][tid];
        Sf[tid] = s;
        Zf[tid] = fmaxf(z, 1e-6f);
    }
    __syncthreads();

    // ---- phase 2: out[c] = (phi_q . S) / (phi_q . Z) ----
    for (int c = tid; c < C_; c += 256) {
        const float xv = xs[c];
        float num = 0.0f, den = 0.0f;
        #pragma unroll 8
        for (int dd = 0; dd < D_; ++dd) {
            const float pq = phi(xv * wqs[dd] + bqs[dd]);
            num += pq * Sf[dd];
            den += pq * Zf[dd];
        }
        out_ws[(size_t)bt * C_ + c] = f2b(num / den);   // coalesced, [bt][c]
    }
}

// GEMM: y[b,o,t] = x[b,o,t] + b_proj[o] + sum_c W[o,c] * out_ws[b*T+t, c]
// A = Wbf row-major [M=512][K=512]; B^T = out_ws [N=4096][K=512].
// One wave -> 16(M) x 64(N) output; no LDS; W (0.5 MB bf16) lives in L2.
__global__ __launch_bounds__(256) void proj_kernel(
    const bf16* __restrict__ out_ws,
    const bf16* __restrict__ wbf,
    const float* __restrict__ b_proj,
    const float* __restrict__ x,
    float* __restrict__ y)
{
    const int lane = threadIdx.x & 63;
    const int wid  = threadIdx.x >> 6;
    const int task = blockIdx.x * 4 + wid;   // 2048 wave-tasks
    const int mt = task & 31;                // 32 M-tiles of 16
    const int ng = task >> 5;                // 64 N-groups of 64
    const int m0 = mt * 16;
    const int n0 = ng * 64;
    const int lr = lane & 15;
    const int lq = lane >> 4;

    const bf16* arow = wbf + (size_t)(m0 + lr) * C_ + lq * 8;
    const bf16* b0p = out_ws + (size_t)(n0 +  0 + lr) * C_ + lq * 8;
    const bf16* b1p = out_ws + (size_t)(n0 + 16 + lr) * C_ + lq * 8;
    const bf16* b2p = out_ws + (size_t)(n0 + 32 + lr) * C_ + lq * 8;
    const bf16* b3p = out_ws + (size_t)(n0 + 48 + lr) * C_ + lq * 8;

    f32x4 acc0 = {0.f,0.f,0.f,0.f}, acc1 = {0.f,0.f,0.f,0.f};
    f32x4 acc2 = {0.f,0.f,0.f,0.f}, acc3 = {0.f,0.f,0.f,0.f};

    #pragma unroll
    for (int k0 = 0; k0 < C_; k0 += 32) {
        bf16x8v a  = *(const bf16x8v*)(const void*)(arow + k0);
        bf16x8v f0 = *(const bf16x8v*)(const void*)(b0p + k0);
        bf16x8v f1 = *(const bf16x8v*)(const void*)(b1p + k0);
        bf16x8v f2 = *(const bf16x8v*)(const void*)(b2p + k0);
        bf16x8v f3 = *(const bf16x8v*)(const void*)(b3p + k0);
        acc0 = __builtin_amdgcn_mfma_f32_16x16x32_bf16(a, f0, acc0, 0, 0, 0);
        acc1 = __builtin_amdgcn_mfma_f32_16x16x32_bf16(a, f1, acc1, 0, 0, 0);
        acc2 = __builtin_amdgcn_mfma_f32_16x16x32_bf16(a, f2, acc2, 0, 0, 0);
        acc3 = __builtin_amdgcn_mfma_f32_16x16x32_bf16(a, f3, acc3, 0, 0, 0);
    }

    // epilogue: C/D layout col = lane&15, row = (lane>>4)*4 + reg
    const int bcol = n0 >> 11;               // whole 64-col group in one batch
    const int tbase = n0 & (T_ - 1);
    f32x4 accs[4] = {acc0, acc1, acc2, acc3};
    #pragma unroll
    for (int j = 0; j < 4; ++j) {
        const int col_t = tbase + j * 16 + lr;
        #pragma unroll
        for (int r = 0; r < 4; ++r) {
            const int row = m0 + lq * 4 + r;
            const size_t idx = (size_t)bcol * C_ * T_ + (size_t)row * T_ + col_t;
            y[idx] = accs[j][r] + b_proj[row] + x[idx];
        }
    }
}

extern "C" void kernel_launch(void* const* d_in, const int* in_sizes, int n_in,
                              void* d_out, int out_size, void* d_ws, size_t ws_size,
                              hipStream_t stream) {
    const float* x      = (const float*)d_in[0];
    const float* wq     = (const float*)d_in[1];
    const float* bq     = (const float*)d_in[2];
    const float* wk     = (const float*)d_in[3];
    const float* bk     = (const float*)d_in[4];
    const float* wv     = (const float*)d_in[5];
    const float* bv     = (const float*)d_in[6];
    const float* w_proj = (const float*)d_in[7];
    const float* b_proj = (const float*)d_in[8];
    float* y = (float*)d_out;

    bf16* out_ws = (bf16*)d_ws;                              // 4 MB: [B*T][C] bf16
    bf16* wbf    = (bf16*)((char*)d_ws + (size_t)BT_ * C_ * 2); // 0.5 MB: W bf16

    attn_kernel<<<BT_, 256, 0, stream>>>(x, wq, bq, wk, bk, wv, bv,
                                         w_proj, out_ws, wbf);
    proj_kernel<<<512, 256, 0, stream>>>(out_ws, wbf, b_proj, x, y);
}

// Round 3
// 139.137 us; speedup vs baseline: 1.1741x; 1.1741x over previous
//
#include <hip/hip_runtime.h>
#include <hip/hip_bf16.h>

// WanChannelLinearAttention  B=2, C=512, T=2048, D=64 (all fp32 I/O)
// R3: attn = packed-fma + folded-constant phi (v_pk_fma_f32, raw v_exp);
//     proj = LDS-staged MFMA GEMM (64x64 tiles, 512 blocks, global_load_lds).

#define B_ 2
#define C_ 512
#define T_ 2048
#define D_ 64
#define BT_ (B_ * T_)
#define L2E 1.44269504088896f

typedef __hip_bfloat16 bf16;
typedef __bf16 bf16x8v __attribute__((ext_vector_type(8)));
typedef float f32x4 __attribute__((ext_vector_type(4)));
typedef float f32x2 __attribute__((ext_vector_type(2)));

__device__ __forceinline__ bf16 f2b(float v) { return __float2bfloat16(v); }

#if __has_builtin(__builtin_amdgcn_exp2f)
#define EXP2(v) __builtin_amdgcn_exp2f(v)
#else
#define EXP2(v) exp2f(v)
#endif

__device__ __forceinline__ void gld_lds16(const void* g, void* l) {
    __builtin_amdgcn_global_load_lds(
        (const __attribute__((address_space(1))) unsigned int*)g,
        (__attribute__((address_space(3))) unsigned int*)l, 16, 0, 0);
}

__global__ __launch_bounds__(256) void attn_kernel(
    const float* __restrict__ x,
    const float* __restrict__ wq, const float* __restrict__ bq,
    const float* __restrict__ wk, const float* __restrict__ bk,
    const float* __restrict__ wv, const float* __restrict__ bv,
    const float* __restrict__ w_proj,
    bf16* __restrict__ out_ws, bf16* __restrict__ wbf)
{
    __shared__ alignas(16) float xs[C_];
    __shared__ alignas(16) float vvs[C_];
    __shared__ f32x4 qpack[D_];      // {wq, bq+1, wq*L2E, bq*L2E}
    __shared__ f32x2 szpack[D_];     // {S, max(Z,eps)}
    __shared__ float Sred[4][D_];
    __shared__ float Zred[4][D_];

    const int tid = threadIdx.x;
    const int bt = blockIdx.x;
    const int b = bt >> 11;          // T_ = 2048
    const int t = bt & (T_ - 1);

    // fused w_proj fp32->bf16 (blocks 0..255): 256 thr x float4
    if (bt < 256) {
        const float4 v = ((const float4*)w_proj)[bt * 256 + tid];
        bf16* dst = wbf + (size_t)(bt * 256 + tid) * 4;
        dst[0] = f2b(v.x); dst[1] = f2b(v.y); dst[2] = f2b(v.z); dst[3] = f2b(v.w);
    }

    // stage x[b,:,t] and v[c] = x*wv+bv
    const float wvs = wv[0], bvs = bv[0];
    for (int c = tid; c < C_; c += 256) {
        const float xv = x[(size_t)b * C_ * T_ + (size_t)c * T_ + t];
        xs[c] = xv;
        vvs[c] = fmaf(xv, wvs, bvs);
    }
    if (tid < D_) {
        const float w = wq[tid], bb = bq[tid];
        f32x4 q; q.x = w; q.y = bb + 1.0f; q.z = w * L2E; q.w = bb * L2E;
        qpack[tid] = q;
    }
    __syncthreads();

    // ---- phase 1: S[d], Z[d] over 128 channels per wave ----
    const int d = tid & 63;
    const int g = tid >> 6;
    const float wkd = wk[d], bkd = bk[d];
    const float bk1 = bkd + 1.0f, wk2 = wkd * L2E, bk2 = bkd * L2E;
    f32x4 S4 = {0.f, 0.f, 0.f, 0.f}, Z4 = {0.f, 0.f, 0.f, 0.f};
    const f32x4* xs4 = (const f32x4*)&xs[g * 128];
    const f32x4* vv4p = (const f32x4*)&vvs[g * 128];
    #pragma unroll 8
    for (int i = 0; i < 32; ++i) {
        const f32x4 x4 = xs4[i];
        const f32x4 vv4 = vv4p[i];
        const f32x4 p1 = x4 * wkd + bk1;   // y+1, packed fma
        const f32x4 y2 = x4 * wk2 + bk2;   // y*log2e, packed fma
        f32x4 pk;
        pk.x = p1.x > 1.0f ? p1.x : EXP2(y2.x);
        pk.y = p1.y > 1.0f ? p1.y : EXP2(y2.y);
        pk.z = p1.z > 1.0f ? p1.z : EXP2(y2.z);
        pk.w = p1.w > 1.0f ? p1.w : EXP2(y2.w);
        S4 = pk * vv4 + S4;
        Z4 = Z4 + pk;
    }
    Sred[g][d] = S4.x + S4.y + S4.z + S4.w;
    Zred[g][d] = Z4.x + Z4.y + Z4.z + Z4.w;
    __syncthreads();
    if (tid < D_) {
        const float s = Sred[0][tid] + Sred[1][tid] + Sred[2][tid] + Sred[3][tid];
        const float z = Zred[0][tid] + Zred[1][tid] + Zred[2][tid] + Zred[3][tid];
        f32x2 sz; sz.x = s; sz.y = fmaxf(z, 1e-6f);
        szpack[tid] = sz;
    }
    __syncthreads();

    // ---- phase 2: out[c] = (phi_q . S)/(phi_q . Z), 2 channels/thread ----
    const float xa = xs[tid], xb = xs[tid + 256];
    f32x2 xp; xp.x = xa; xp.y = xb;
    f32x2 num = {0.f, 0.f}, den = {0.f, 0.f};
    #pragma unroll 8
    for (int dd = 0; dd < D_; ++dd) {
        const f32x4 q = qpack[dd];     // ds_read_b128, wave-uniform broadcast
        const f32x2 sz = szpack[dd];   // ds_read_b64, broadcast
        const f32x2 p1 = xp * q.x + q.y;
        const f32x2 y2 = xp * q.z + q.w;
        f32x2 pk;
        pk.x = p1.x > 1.0f ? p1.x : EXP2(y2.x);
        pk.y = p1.y > 1.0f ? p1.y : EXP2(y2.y);
        num = pk * sz.x + num;
        den = pk * sz.y + den;
    }
    out_ws[(size_t)bt * C_ + tid]       = f2b(num.x / den.x);
    out_ws[(size_t)bt * C_ + tid + 256] = f2b(num.y / den.y);
}

// GEMM: y[b,o,t] = x[b,o,t] + b_proj[o] + sum_c W[o,c]*out[bt,c]
// A = wbf [512][512] (K-contig), B^T = out_ws [4096][512] (K-contig).
// 64x64 tile per block, 512 blocks (2/CU), LDS staging via global_load_lds.
__global__ __launch_bounds__(256) void proj_kernel(
    const bf16* __restrict__ out_ws,
    const bf16* __restrict__ wbf,
    const float* __restrict__ b_proj,
    const float* __restrict__ x,
    float* __restrict__ y)
{
    __shared__ alignas(16) bf16 As[64 * 32];  // [m][k] 4 KB
    __shared__ alignas(16) bf16 Bs[64 * 32];  // [n][k] 4 KB

    const int tid = threadIdx.x;
    const int lane = tid & 63, w = tid >> 6;
    const int lr = lane & 15, lq = lane >> 4;
    const int mblk = blockIdx.x & 7;          // 8 m-blocks of 64
    const int nblk = blockIdx.x >> 3;         // 64 n-blocks of 64
    const int wm = (w >> 1) * 32, wn = (w & 1) * 32;

    const int ldrow = tid >> 2, ldk = (tid & 3) * 8;   // 256 chunks of 16B
    const bf16* asrc = wbf    + (size_t)(mblk * 64 + ldrow) * C_ + ldk;
    const bf16* bsrc = out_ws + (size_t)(nblk * 64 + ldrow) * C_ + ldk;

    f32x4 acc00 = {0.f,0.f,0.f,0.f}, acc01 = {0.f,0.f,0.f,0.f};
    f32x4 acc10 = {0.f,0.f,0.f,0.f}, acc11 = {0.f,0.f,0.f,0.f};

    for (int k0 = 0; k0 < C_; k0 += 32) {
        __syncthreads();                       // prior ds_reads done
        gld_lds16(asrc + k0, &As[tid * 8]);
        gld_lds16(bsrc + k0, &Bs[tid * 8]);
        __syncthreads();                       // drains vmcnt before reads
        const bf16x8v a0 = *(const bf16x8v*)&As[(wm      + lr) * 32 + lq * 8];
        const bf16x8v a1 = *(const bf16x8v*)&As[(wm + 16 + lr) * 32 + lq * 8];
        const bf16x8v b0 = *(const bf16x8v*)&Bs[(wn      + lr) * 32 + lq * 8];
        const bf16x8v b1 = *(const bf16x8v*)&Bs[(wn + 16 + lr) * 32 + lq * 8];
        acc00 = __builtin_amdgcn_mfma_f32_16x16x32_bf16(a0, b0, acc00, 0, 0, 0);
        acc01 = __builtin_amdgcn_mfma_f32_16x16x32_bf16(a0, b1, acc01, 0, 0, 0);
        acc10 = __builtin_amdgcn_mfma_f32_16x16x32_bf16(a1, b0, acc10, 0, 0, 0);
        acc11 = __builtin_amdgcn_mfma_f32_16x16x32_bf16(a1, b1, acc11, 0, 0, 0);
    }

    // epilogue: C/D layout col = lane&15 (n/t), row = (lane>>4)*4 + reg (m)
    f32x4 accs[2][2] = {{acc00, acc01}, {acc10, acc11}};
    #pragma unroll
    for (int i = 0; i < 2; ++i) {
        #pragma unroll
        for (int j = 0; j < 2; ++j) {
            const int n = nblk * 64 + wn + j * 16 + lr;
            const int bb = n >> 11, tt = n & (T_ - 1);
            #pragma unroll
            for (int r = 0; r < 4; ++r) {
                const int m = mblk * 64 + wm + i * 16 + lq * 4 + r;
                const size_t idx = (size_t)bb * C_ * T_ + (size_t)m * T_ + tt;
                y[idx] = accs[i][j][r] + b_proj[m] + x[idx];
            }
        }
    }
}

extern "C" void kernel_launch(void* const* d_in, const int* in_sizes, int n_in,
                              void* d_out, int out_size, void* d_ws, size_t ws_size,
                              hipStream_t stream) {
    const float* x      = (const float*)d_in[0];
    const float* wq     = (const float*)d_in[1];
    const float* bq     = (const float*)d_in[2];
    const float* wk     = (const float*)d_in[3];
    const float* bk     = (const float*)d_in[4];
    const float* wv     = (const float*)d_in[5];
    const float* bv     = (const float*)d_in[6];
    const float* w_proj = (const float*)d_in[7];
    const float* b_proj = (const float*)d_in[8];
    float* y = (float*)d_out;

    bf16* out_ws = (bf16*)d_ws;                                 // 4 MB [B*T][C]
    bf16* wbf    = (bf16*)((char*)d_ws + (size_t)BT_ * C_ * 2); // 0.5 MB W bf16

    attn_kernel<<<BT_, 256, 0, stream>>>(x, wq, bq, wk, bk, wv, bv,
                                         w_proj, out_ws, wbf);
    proj_kernel<<<512, 256, 0, stream>>>(out_ws, wbf, b_proj, x, y);
}